// Round 5
// baseline (210.879 us; speedup 1.0000x reference)
//
#include <hip/hip_runtime.h>

#define IN_DIM 8192
#define OUT_DIM 8192
#define BATCH 2048
#define TPB 512                      // 8 waves/block
#define RPB 4                        // rows per block; grid = 512 = 2 blocks/CU
#define NQ (OUT_DIM / 4 / TPB)       // 4 float4-output quads per thread per row
#define NSTG (IN_DIM / 4 / TPB)      // 4 direct-to-LDS 16B loads per thread per row

typedef float fvec4 __attribute__((ext_vector_type(4)));

#define GLOAD_LDS16(gp, lp)                                                        \
    __builtin_amdgcn_global_load_lds(                                              \
        (const __attribute__((address_space(1))) unsigned int*)(gp),               \
        (__attribute__((address_space(3))) unsigned int*)(lp), 16, 0, 0)

#define MEMFENCE() asm volatile("" ::: "memory")

// ---------------------------------------------------------------------------
// Single fused kernel. Per block (4 rows, 512 threads):
//
// PROLOGUE:
//   1. issue DMA(row0 -> buf0)                    (flies under the coeff phase)
//   2. pack this thread's 16 column indices into pi[4] (byte offsets, 16b halves)
//   3. softmax(w[j,0:16]) -> {c0,ca,cb,cab} for this thread's 16 columns,
//      register-resident in cA[8]/cB[8] (row-invariant, reused for all rows).
//      Redundant across blocks (256x) but: one-time, ~3.5K cy/wave, overlapped
//      with DMA(0), and w is L2/L3-resident after the first wave of blocks.
//      (The compiler's own vmcnt wait for w values also drains DMA(0) --
//       harmless: it had the whole coeff phase to fly and is needed at bar_B.)
//
// LOOP (R3's issue-early depth-1 schedule, counted vmcnt, never drained mid-loop):
//   iter r: bar_A (all waves done READING buf[(r+1)&1])
//           issue DMA(row r+1 -> buf[(r+1)&1])
//           s_waitcnt vmcnt(8)   (steady: retires exactly DMA(r);
//                                 st(r-1) and DMA(r+1) stay in flight)
//           bar_B -> compute row r from buf[r&1], 4x nontemporal float4 stores
//   edges: r==0 and r==RPB-1 -> vmcnt(4).
// ---------------------------------------------------------------------------
__global__ __launch_bounds__(TPB, 4) void logic_kernel(
    const float* __restrict__ x,
    const float* __restrict__ w,
    const int* __restrict__ idx_a,
    const int* __restrict__ idx_b,
    float* __restrict__ out)
{
    __shared__ float xrow[2][IN_DIM];        // 64 KB -> 2 blocks/CU (LDS-limited)

    const int tid  = threadIdx.x;
    const int row0 = blockIdx.x * RPB;

    // ---- 1. DMA row0 -> buf0 FIRST (overlaps the whole coeff phase) ----
    {
        const float* xr = x + (size_t)row0 * IN_DIM;
#pragma unroll
        for (int i = 0; i < NSTG; ++i)
            GLOAD_LDS16(xr + 4 * (i * TPB + tid), &xrow[0][4 * (i * TPB + tid)]);
    }
    MEMFENCE();

    // ---- 2. pack indices: pi[q] = (idx_a*4)&0xffff | (idx_b*4)<<18 ----
    int4 pi[NQ];
#pragma unroll
    for (int q = 0; q < NQ; ++q) {
        int j4 = q * TPB + tid;                       // quad of columns 4*j4..4*j4+3
        int4 ia = ((const int4*)idx_a)[j4];
        int4 ib = ((const int4*)idx_b)[j4];
        pi[q].x = ((ia.x << 2) & 0xffff) | (ib.x << 18);
        pi[q].y = ((ia.y << 2) & 0xffff) | (ib.y << 18);
        pi[q].z = ((ia.z << 2) & 0xffff) | (ib.z << 18);
        pi[q].w = ((ia.w << 2) & 0xffff) | (ib.w << 18);
    }

    // ---- 3. softmax -> affine coeffs for this thread's 16 columns ----
    // cA[2q+(k>>1)] = (c0,ca) pairs, cB likewise (cb,cab), matching the
    // compute loop's layout (2 columns per float4).
    float4 cA[2 * NQ];
    float4 cB[2 * NQ];
#pragma unroll
    for (int q = 0; q < NQ; ++q) {
#pragma unroll
        for (int k = 0; k < 4; ++k) {
            int j = 4 * (q * TPB + tid) + k;
            const float4* w4 = (const float4*)(w + (size_t)j * 16);
            float4 q0 = w4[0], q1 = w4[1], q2 = w4[2], q3 = w4[3];
            float wv[16] = { q0.x, q0.y, q0.z, q0.w,
                             q1.x, q1.y, q1.z, q1.w,
                             q2.x, q2.y, q2.z, q2.w,
                             q3.x, q3.y, q3.z, q3.w };
            float m = -1e30f;
#pragma unroll
            for (int t = 0; t < 16; ++t) m = fmaxf(m, wv[t]);
            float s = 0.f;
#pragma unroll
            for (int t = 0; t < 16; ++t) { wv[t] = __expf(wv[t] - m); s += wv[t]; }
            float inv = 1.0f / s;
#pragma unroll
            for (int t = 0; t < 16; ++t) wv[t] *= inv;

            float c0  = wv[8] + wv[9] + wv[10] + wv[11] + wv[12] + wv[13] + wv[14] + wv[15];
            float ca  = wv[2] + wv[3] + wv[6] + wv[7] - wv[8] - wv[9] - wv[12] - wv[13];
            float cb  = wv[4] + wv[5] + wv[6] + wv[7] - wv[8] - wv[9] - wv[10] - wv[11];
            float cab = wv[1] - wv[2] - wv[4] - 2.f * wv[6] - wv[7]
                      + wv[8] + 2.f * wv[9] + wv[11] + wv[13] - wv[14];

            if ((k & 1) == 0) { cA[2 * q + (k >> 1)].x = c0; cA[2 * q + (k >> 1)].y = ca;
                                cB[2 * q + (k >> 1)].x = cb; cB[2 * q + (k >> 1)].y = cab; }
            else              { cA[2 * q + (k >> 1)].z = c0; cA[2 * q + (k >> 1)].w = ca;
                                cB[2 * q + (k >> 1)].z = cb; cB[2 * q + (k >> 1)].w = cab; }
        }
    }
    MEMFENCE();

#pragma unroll
    for (int r = 0; r < RPB; ++r) {
        // bar_A: every wave finished READING buf[(r+1)&1] (last read in iter r-1)
        __builtin_amdgcn_s_barrier();

        // issue next row's DMA BEFORE waiting on the current row's DMA
        if (r + 1 < RPB) {
            const float* xn = x + (size_t)(row0 + r + 1) * IN_DIM;
#pragma unroll
            for (int i = 0; i < NSTG; ++i)
                GLOAD_LDS16(xn + 4 * (i * TPB + tid), &xrow[(r + 1) & 1][4 * (i * TPB + tid)]);
        }
        MEMFENCE();

        // counted retire of DMA(r) only (never drain to 0 mid-loop)
        if (r == 0 || r + 1 == RPB) asm volatile("s_waitcnt vmcnt(4)" ::: "memory");
        else                        asm volatile("s_waitcnt vmcnt(8)" ::: "memory");
        __builtin_amdgcn_s_barrier();   // bar_B: LDS row r valid for all waves
        MEMFENCE();

        const char* xb = (const char*)xrow[r & 1];
        fvec4* out4 = (fvec4*)(out + (size_t)(row0 + r) * OUT_DIM);

#pragma unroll
        for (int q = 0; q < NQ; ++q) {
            int4 p = pi[q];
            // byte-offset gathers (pi holds idx*4 packed in 16-bit halves)
            float a0 = *(const float*)(xb + (p.x & 0xffff)), b0 = *(const float*)(xb + ((unsigned)p.x >> 16));
            float a1 = *(const float*)(xb + (p.y & 0xffff)), b1 = *(const float*)(xb + ((unsigned)p.y >> 16));
            float a2 = *(const float*)(xb + (p.z & 0xffff)), b2 = *(const float*)(xb + ((unsigned)p.z >> 16));
            float a3 = *(const float*)(xb + (p.w & 0xffff)), b3 = *(const float*)(xb + ((unsigned)p.w >> 16));

            float4 A0 = cA[2 * q], A1 = cA[2 * q + 1];
            float4 B0 = cB[2 * q], B1 = cB[2 * q + 1];

            // o = (c0 + ca*a) + b*(cb + cab*a)   -- 3 FMAs per output
            fvec4 o;
            o.x = fmaf(fmaf(B0.y, a0, B0.x), b0, fmaf(A0.y, a0, A0.x));
            o.y = fmaf(fmaf(B0.w, a1, B0.z), b1, fmaf(A0.w, a1, A0.z));
            o.z = fmaf(fmaf(B1.y, a2, B1.x), b2, fmaf(A1.y, a2, A1.x));
            o.w = fmaf(fmaf(B1.w, a3, B1.z), b3, fmaf(A1.w, a3, A1.z));
            __builtin_nontemporal_store(o, &out4[q * TPB + tid]);
        }
        MEMFENCE();
    }
}

extern "C" void kernel_launch(void* const* d_in, const int* in_sizes, int n_in,
                              void* d_out, int out_size, void* d_ws, size_t ws_size,
                              hipStream_t stream)
{
    const float* x       = (const float*)d_in[0];  // (2048, 8192) fp32
    const float* weights = (const float*)d_in[1];  // (8192, 16)   fp32
    const int*   idx_a   = (const int*)d_in[2];    // (8192,) int32 on device
    const int*   idx_b   = (const int*)d_in[3];    // (8192,) int32 on device
    float* out = (float*)d_out;                    // (2048, 8192) fp32

    logic_kernel<<<BATCH / RPB, TPB, 0, stream>>>(x, weights, idx_a, idx_b, out);
}